// Round 1
// baseline (201.396 us; speedup 1.0000x reference)
//
#include <hip/hip_runtime.h>

// MultiScaleSampler: per-point 5->32->32->32->3 MLP + softmax(3), scattered to
// zeroed (H*W,3) output at unique indices yi. Strategy: 1 thread = 1 point,
// weights loaded via wave-uniform global loads (compiler -> s_load -> SGPR
// operands of v_fmac_f32), full unroll so activations stay in VGPRs.

#define H_IMG 1024
#define W_IMG 2048
#define NFEAT 32
#define NPROB 3

__global__ __launch_bounds__(256) void msampler_mlp(
    const float* __restrict__ grid,   // (2, N): x row then y row
    const int*   __restrict__ yi,     // (N,)
    const float* __restrict__ m,      // (3,3)
    const float* __restrict__ W1, const float* __restrict__ b1,   // (5,32),(32)
    const float* __restrict__ W2, const float* __restrict__ b2,   // (32,32),(32)
    const float* __restrict__ W3, const float* __restrict__ b3,   // (32,32),(32)
    const float* __restrict__ W4, const float* __restrict__ b4,   // (32,3),(3)
    float* __restrict__ out, int N)
{
    int i = blockIdx.x * blockDim.x + threadIdx.x;
    if (i >= N) return;

    float gx = grid[i];
    float gy = grid[N + i];
    int   y  = yi[i];
    int   py = y >> 11;            // / W_IMG (2048)
    int   px = y & (W_IMG - 1);    // % W_IMG

    // dsda = |det(m)| / |m20*px + m21*py + m22|^3   (uniform m -> SGPR math)
    float m00=m[0], m01=m[1], m02=m[2];
    float m10=m[3], m11=m[4], m12=m[5];
    float m20=m[6], m21=m[7], m22=m[8];
    float det = m00*(m11*m22 - m12*m21)
              - m01*(m10*m22 - m12*m20)
              + m02*(m10*m21 - m11*m20);
    float denom = m20*(float)px + m21*(float)py + m22;
    float ad    = fabsf(denom);
    float dsda  = fabsf(det) / (ad*ad*ad);

    float fx = gx - floorf(gx);
    float fy = gy - floorf(gy);
    // features: [tl_x, tl_y, br_x, br_y, dsda]
    float x0 = fx, x1 = fy, x2 = 1.f - fx, x3 = 1.f - fy, x4 = dsda;

    float h1[NFEAT], h2[NFEAT];

    // layer 1: (5 -> 32) + relu
#pragma unroll
    for (int j = 0; j < NFEAT; ++j) {
        float a = b1[j];
        a = fmaf(x0, W1[0*NFEAT + j], a);
        a = fmaf(x1, W1[1*NFEAT + j], a);
        a = fmaf(x2, W1[2*NFEAT + j], a);
        a = fmaf(x3, W1[3*NFEAT + j], a);
        a = fmaf(x4, W1[4*NFEAT + j], a);
        h1[j] = fmaxf(a, 0.f);
    }
    // layer 2: (32 -> 32) + relu
#pragma unroll
    for (int j = 0; j < NFEAT; ++j) {
        float a = b2[j];
#pragma unroll
        for (int k = 0; k < NFEAT; ++k)
            a = fmaf(h1[k], W2[k*NFEAT + j], a);
        h2[j] = fmaxf(a, 0.f);
    }
    // layer 3: (32 -> 32) + relu (reuse h1 as h3)
#pragma unroll
    for (int j = 0; j < NFEAT; ++j) {
        float a = b3[j];
#pragma unroll
        for (int k = 0; k < NFEAT; ++k)
            a = fmaf(h2[k], W3[k*NFEAT + j], a);
        h1[j] = fmaxf(a, 0.f);
    }
    // layer 4: (32 -> 3)
    float l0 = b4[0], l1 = b4[1], l2 = b4[2];
#pragma unroll
    for (int k = 0; k < NFEAT; ++k) {
        float h = h1[k];
        l0 = fmaf(h, W4[k*NPROB + 0], l0);
        l1 = fmaf(h, W4[k*NPROB + 1], l1);
        l2 = fmaf(h, W4[k*NPROB + 2], l2);
    }
    // softmax(3)
    float mx = fmaxf(l0, fmaxf(l1, l2));
    float e0 = __expf(l0 - mx), e1 = __expf(l1 - mx), e2 = __expf(l2 - mx);
    float inv = 1.f / (e0 + e1 + e2);

    int o = y * 3;
    out[o + 0] = e0 * inv;
    out[o + 1] = e1 * inv;
    out[o + 2] = e2 * inv;
}

extern "C" void kernel_launch(void* const* d_in, const int* in_sizes, int n_in,
                              void* d_out, int out_size, void* d_ws, size_t ws_size,
                              hipStream_t stream) {
    const float* grid = (const float*)d_in[0];
    const int*   yi   = (const int*)  d_in[1];
    const float* m    = (const float*)d_in[2];
    const float* W1   = (const float*)d_in[3];
    const float* b1   = (const float*)d_in[4];
    const float* W2   = (const float*)d_in[5];
    const float* b2   = (const float*)d_in[6];
    const float* W3   = (const float*)d_in[7];
    const float* b3   = (const float*)d_in[8];
    const float* W4   = (const float*)d_in[9];
    const float* b4   = (const float*)d_in[10];
    float* out = (float*)d_out;

    int N = in_sizes[1];  // yi element count

    // zero the spatial output (scatter only covers N of H*W pixels)
    hipMemsetAsync(d_out, 0, (size_t)out_size * sizeof(float), stream);

    int block = 256;
    int grid_sz = (N + block - 1) / block;
    msampler_mlp<<<grid_sz, block, 0, stream>>>(
        grid, yi, m, W1, b1, W2, b2, W3, b3, W4, b4, out, N);
}